// Round 1
// 236.647 us; speedup vs baseline: 1.0808x; 1.0808x over previous
//
#include <hip/hip_runtime.h>
#include <hip/hip_bf16.h>

// Problem constants
#define BB   4096
#define INW  1024
#define HH   1024
#define KIN  2048      // IN + H
#define NG   5120      // 3H + 2H
#define KH   32        // inner hidden
#define FPG  10        // 16-col fragments per 160-col gate-group
#define NTG  32        // number of gate-groups (= H/32)

typedef __bf16 bf16;
typedef __bf16 bf16x4 __attribute__((ext_vector_type(4)));
typedef __bf16 bf16x8 __attribute__((ext_vector_type(8)));
typedef float  floatx4 __attribute__((ext_vector_type(4)));

#define GLD16(gp, lp)                                                          \
  __builtin_amdgcn_global_load_lds(                                            \
      (__attribute__((address_space(1))) const void*)(gp),                     \
      (__attribute__((address_space(3))) void*)(lp), 16, 0, 0)

// ---------------------------------------------------------------------------
// 1. prep: concat+cast x|h_prev -> comb bf16 (flat), and shuffle-cast Wg,Wc
//    -> Wb in GATE-PERMUTED MFMA B-fragment order.
//    N is permuted into 32 groups of 160 cols; group nt, within-group col
//    c = (hl>>4)*80 + gate*16 + (hl&15) for h = nt*32 + hl, gate in {i,f,o,p0,p1}.
//    16B chunk o = [nt][kk][f][lane] (f in [0,10)) holds
//    B[n_perm = nt*160 + f*16 + (lane&15)][k = kk*32 + (lane>>4)*8 .. +7].
//    This makes all 5 gate values of one (b,h) land in ONE lane of the MFMA
//    C/D fragment -> epilogue fuses into the GEMM with zero cross-lane traffic.
// ---------------------------------------------------------------------------
#define NC4  (BB * KIN / 4)        // float4 groups for comb      (2,097,152)
#define NW8  (NG * KIN / 8)        // 16B output chunks for Wb    (1,310,720)

__global__ __launch_bounds__(256) void prep(
    const float* __restrict__ x, const float* __restrict__ h,
    const float* __restrict__ Wg, const float* __restrict__ Wc,
    bf16* __restrict__ comb, bf16* __restrict__ Wb) {
  int i = blockIdx.x * 256 + threadIdx.x;
  if (i < NC4) {                       // ---- comb: concat + cast ----
    int e = i * 4;
    int b = e >> 11;          // / KIN
    int c = e & (KIN - 1);
    const float* src = (c < INW) ? (x + (size_t)b * INW + c)
                                 : (h + (size_t)b * HH + (c - INW));
    float4 v = *(const float4*)src;
    bf16x4 o4;
    o4[0] = (bf16)v.x; o4[1] = (bf16)v.y; o4[2] = (bf16)v.z; o4[3] = (bf16)v.w;
    *(bf16x4*)(comb + e) = o4;
  } else {                             // ---- Wb: gate-permuted fragment shuffle
    int o = i - NC4;
    if (o < NW8) {
      int lane = o & 63;
      int t    = o >> 6;
      int f    = t % FPG;              // fragment within 160-col group
      t        = t / FPG;
      int kk   = t & 63;               // k-chunk of 32
      int nt   = t >> 6;               // gate-group
      int q    = f / 5;                // which 16-h half of the group
      int g    = f - q * 5;            // gate: 0=i 1=f 2=o 3=p0 4=p1
      int hcol = nt * 32 + q * 16 + (lane & 15);
      int k    = kk * 32 + (lane >> 4) * 8;
      const float* src = (g < 3)
          ? (Wg + (size_t)(g * HH + hcol) * KIN + k)
          : (Wc + (size_t)(2 * hcol + (g - 3)) * KIN + k);
      float4 v0 = *(const float4*)src;
      float4 v1 = *(const float4*)(src + 4);
      bf16x8 ov;
      ov[0] = (bf16)v0.x; ov[1] = (bf16)v0.y; ov[2] = (bf16)v0.z; ov[3] = (bf16)v0.w;
      ov[4] = (bf16)v1.x; ov[5] = (bf16)v1.y; ov[6] = (bf16)v1.z; ov[7] = (bf16)v1.w;
      *(bf16x8*)(Wb + (size_t)o * 8) = ov;
    }
  }
}

// ---------------------------------------------------------------------------
// 2. Fused GEMM + LSTM epilogue.
//    Tile 128x160 (BM=128, BN=160 = one gate-group of 32 h's). 4 waves as
//    2x2; each wave owns 64 rows x 80 cols (5 ni-fragments = the 5 gates of
//    16 h's). K-loop structure = R8 champion (BK=128, LDS 32 KB A tile with
//    XOR swizzle, B direct HBM->reg in fragment order, prefetched before the
//    barrier pair).
//    Epilogue: C/D layout col=lane&15, row=qd*4+r  =>  lane (q,lr) holds all
//    5 gates of h = nt*32+q*16+lr for its 16 b-rows. Inner MLP + sigmoids +
//    tanh run fully in-register on f32 accumulators; writes h_next/c_next.
//    Eliminates the 83 MB G round-trip and the 3rd kernel dispatch.
// ---------------------------------------------------------------------------
__global__ __launch_bounds__(256, 2) void gemm_fused(
    const bf16* __restrict__ A, const bf16* __restrict__ Bm,
    const float* __restrict__ c_prev, const float* __restrict__ bg,
    const float* __restrict__ bc, const float* __restrict__ W1,
    const float* __restrict__ b1, const float* __restrict__ W2,
    const float* __restrict__ b2, float* __restrict__ h_next,
    float* __restrict__ c_next) {
  __shared__ bf16 As[128 * 128];   // 32 KB

  const int tid  = threadIdx.x;
  const int wave = tid >> 6;
  const int lane = tid & 63;

  // XCD-aware swizzle: 1024 blocks, 8 XCDs, 128 blocks/XCD (bijective).
  // Consecutive blocks within an XCD share nt (B-slice stays L2-hot).
  const int bid = blockIdx.y * gridDim.x + blockIdx.x;
  const int swz = (bid & 7) * 128 + (bid >> 3);
  const int m0  = (swz & 31) * 128;
  const int nt  = swz >> 5;

  const int wm = (wave >> 1) * 64;   // wave row origin in tile
  const int q  = wave & 1;           // wave col half: which 16 h's
  const int lr = lane & 15;
  const int qd = lane >> 4;

  // B base: chunk = ((nt*64 + kk)*10 + q*5 + ni)*64 + lane
  const bf16* Bq = Bm + ((size_t)(nt * 640 + q * 5) * 64 + lane) * 8;

  floatx4 acc[4][5] = {};

  for (int kt = 0; kt < KIN / 128; ++kt) {    // 16 iterations of BK=128
    bf16x8 bfr[4][5];
#pragma unroll
    for (int ks = 0; ks < 4; ++ks)
#pragma unroll
      for (int ni = 0; ni < 5; ++ni)
        bfr[ks][ni] =
            *(const bf16x8*)(Bq + ((size_t)((kt * 4 + ks) * FPG + ni) << 9));

    __syncthreads();  // previous iter's LDS reads must finish before overwrite
#pragma unroll
    for (int j = 0; j < 8; ++j) {       // A: 2048 16B slots (128 rows x 16)
      int s   = j * 256 + tid;
      int row = s >> 4;
      int c   = (s & 15) ^ (row & 15);  // XOR swizzle
      GLD16(A + (size_t)(m0 + row) * KIN + kt * 128 + c * 8,
            As + (size_t)(j * 256 + wave * 64) * 8);
    }
    __syncthreads();

#pragma unroll
    for (int ks = 0; ks < 4; ++ks) {    // 4 k-steps of 32
      bf16x8 af[4];
#pragma unroll
      for (int mi = 0; mi < 4; ++mi) {
        int row  = wm + mi * 16 + lr;
        int slot = (ks * 4 + qd) ^ lr;  // row&15 == lr
        af[mi] = *(const bf16x8*)&As[(row << 7) + (slot << 3)];
      }
#pragma unroll
      for (int mi = 0; mi < 4; ++mi)
#pragma unroll
        for (int ni = 0; ni < 5; ++ni)
          acc[mi][ni] = __builtin_amdgcn_mfma_f32_16x16x32_bf16(
              af[mi], bfr[ks][ni], acc[mi][ni], 0, 0, 0);
    }
  }

  // ---- fused epilogue: all 5 gates of (b, h) live in this lane ----
  const int h   = nt * 32 + q * 16 + lr;
  const float bgi = bg[h];
  const float bgf = bg[HH + h];
  const float bgo = bg[2 * HH + h];
  const float bc0 = bc[2 * h];
  const float bc1 = bc[2 * h + 1];
  const float gb  = b2[0];

  float p0[16], p1[16], ga[16];
#pragma unroll
  for (int mi = 0; mi < 4; ++mi)
#pragma unroll
    for (int r = 0; r < 4; ++r) {
      p0[mi * 4 + r] = acc[mi][3][r] + bc0;
      p1[mi * 4 + r] = acc[mi][4][r] + bc1;
      ga[mi * 4 + r] = gb;
    }
  // inner MLP: k-outer so the 4 uniform weight scalars stay in SGPRs
#pragma unroll
  for (int k = 0; k < KH; ++k) {
    float w0 = W1[2 * k], w1 = W1[2 * k + 1], bk = b1[k], wk = W2[k];
#pragma unroll
    for (int e = 0; e < 16; ++e) {
      float hv = fmaf(p0[e], w0, fmaf(p1[e], w1, bk));
      hv = fmaxf(hv, 0.0f);
      ga[e] = fmaf(hv, wk, ga[e]);
    }
  }

#pragma unroll
  for (int mi = 0; mi < 4; ++mi)
#pragma unroll
    for (int r = 0; r < 4; ++r) {
      int b    = m0 + wm + mi * 16 + qd * 4 + r;
      size_t o = (size_t)b * HH + h;
      float si = 1.0f / (1.0f + __expf(-(acc[mi][0][r] + bgi)));
      float sf = 1.0f / (1.0f + __expf(-(acc[mi][1][r] + bgf)));
      float so = 1.0f / (1.0f + __expf(-(acc[mi][2][r] + bgo)));
      float cn = fmaf(sf, c_prev[o], si * ga[mi * 4 + r]);
      float e2 = __expf(2.0f * cn);          // tanh(cn) = 1 - 2/(e^{2cn}+1)
      float th = 1.0f - 2.0f / (e2 + 1.0f);
      h_next[o] = so * th;
      c_next[o] = cn;
    }
}

// ---------------------------------------------------------------------------
extern "C" void kernel_launch(void* const* d_in, const int* in_sizes, int n_in,
                              void* d_out, int out_size, void* d_ws, size_t ws_size,
                              hipStream_t stream) {
  const float* x      = (const float*)d_in[0];
  const float* h_prev = (const float*)d_in[1];
  const float* c_prev = (const float*)d_in[2];
  const float* Wg     = (const float*)d_in[3];
  const float* bg     = (const float*)d_in[4];
  const float* Wc     = (const float*)d_in[5];
  const float* bc     = (const float*)d_in[6];
  const float* W1     = (const float*)d_in[7];
  const float* b1     = (const float*)d_in[8];
  const float* W2     = (const float*)d_in[9];
  const float* b2     = (const float*)d_in[10];
  float* out = (float*)d_out;

  // workspace layout (G buffer eliminated)
  char* ws = (char*)d_ws;
  bf16* comb = (bf16*)ws;                                    // 16 MB
  bf16* Wb   = (bf16*)(ws + (size_t)BB * KIN * 2);           // 20 MB

  // 1. prep (concat + casts + gate-permuted B fragment shuffle)
  prep<<<(NC4 + NW8 + 255) / 256, 256, 0, stream>>>(x, h_prev, Wg, Wc, comb, Wb);

  // 2. fused GEMM + epilogue
  dim3 grid(BB / 128, NTG);
  gemm_fused<<<grid, 256, 0, stream>>>(comb, Wb, c_prev, bg, bc, W1, b1, W2,
                                       b2, out, out + (size_t)BB * HH);
}